// Round 8
// baseline (961.977 us; speedup 1.0000x reference)
//
#include <hip/hip_runtime.h>
#include <cstddef>

#define NN 50000
#define TT 12
#define HH 128
#define EE 800000

typedef short v8s __attribute__((ext_vector_type(8)));
typedef float v4f __attribute__((ext_vector_type(4)));
#define MFMA(a, b, c) __builtin_amdgcn_mfma_f32_16x16x32_bf16(a, b, c, 0, 0, 0)

__device__ __forceinline__ unsigned short f2bf(float f) {
  unsigned int u = __float_as_uint(f);
  u += 0x7FFF + ((u >> 16) & 1);
  return (unsigned short)(u >> 16);
}
__device__ __forceinline__ float bf2f(unsigned short b) {
  return __uint_as_float(((unsigned int)b) << 16);
}
// HW packed f32->bf16 (low16 = a, high16 = b). Rounding mode irrelevant for
// hi/lo splits: lo captures the residual exactly.
__device__ __forceinline__ unsigned int cvt_pk_bf16(float a, float b) {
  unsigned int r;
  asm("v_cvt_pk_bf16_f32 %0, %1, %2" : "=v"(r) : "v"(a), "v"(b));
  return r;
}

// ---------------- degree + CSR count (one pass over edges) ----------------
__global__ void k_degcnt(const int* __restrict__ ei, const float* __restrict__ ew,
                         float* __restrict__ deg, int* __restrict__ cnt) {
  int e = blockIdx.x * 256 + threadIdx.x;
  if (e < EE) {
    int d = ei[EE + e];
    atomicAdd(&deg[d], ew[e]);
    atomicAdd(&cnt[d], 1);
  }
}

__global__ void k_dinv(float* __restrict__ deg) {
  int n = blockIdx.x * 256 + threadIdx.x;
  if (n < NN) deg[n] = rsqrtf(deg[n] + 1.0f);  // self-loop weight 1 included
}

__global__ void k_scan(const int* __restrict__ cnt, int* __restrict__ row) {
  __shared__ int ps[1024];
  int tid = threadIdx.x;
  const int CH = 49;  // 1024*49 >= NN
  int b0 = tid * CH;
  int s = 0;
  for (int i = 0; i < CH; i++) { int idx = b0 + i; if (idx < NN) s += cnt[idx]; }
  ps[tid] = s;
  __syncthreads();
  for (int off = 1; off < 1024; off <<= 1) {
    int v = (tid >= off) ? ps[tid - off] : 0;
    __syncthreads();
    ps[tid] += v;
    __syncthreads();
  }
  int bb = (tid > 0) ? ps[tid - 1] : 0;
  for (int i = 0; i < CH; i++) {
    int idx = b0 + i;
    if (idx < NN) { row[idx] = bb; bb += cnt[idx]; }
  }
  if (tid == 1023) row[NN] = bb;
}

__global__ void k_scatter(const int* __restrict__ ei, const float* __restrict__ ew,
                          const float* __restrict__ dinv, const int* __restrict__ row,
                          int* __restrict__ cur, int* __restrict__ csr_s,
                          float* __restrict__ csr_w) {
  int e = blockIdx.x * 256 + threadIdx.x;
  if (e >= EE) return;
  int s = ei[e], d = ei[EE + e];
  int pos = row[d] + atomicAdd(&cur[d], 1);
  csr_s[pos] = s;
  csr_w[pos] = dinv[s] * ew[e] * dinv[d];
}

// one wave per dst node; lane covers 3 of the 192 (f,t) columns
__global__ void k_gather(const int* __restrict__ row, const int* __restrict__ csr_s,
                         const float* __restrict__ csr_w, const float* __restrict__ dinv,
                         const float* __restrict__ x, unsigned short* __restrict__ Ybf) {
  int d = blockIdx.x * 4 + (threadIdx.x >> 6);
  if (d >= NN) return;
  int lane = threadIdx.x & 63;
  float acc0, acc1, acc2;
  {
    float dv = dinv[d]; dv *= dv;  // self loop
    const float* xr = x + (size_t)d * 192;
    acc0 = dv * xr[lane]; acc1 = dv * xr[lane + 64]; acc2 = dv * xr[lane + 128];
  }
  int kb = row[d], ke = row[d + 1];
  for (int k = kb; k < ke; k++) {
    int s = csr_s[k];
    float wv = csr_w[k];
    const float* xr = x + (size_t)s * 192;
    acc0 = fmaf(wv, xr[lane], acc0);
    acc1 = fmaf(wv, xr[lane + 64], acc1);
    acc2 = fmaf(wv, xr[lane + 128], acc2);
  }
  int c, t, f;
  c = lane;       t = c % TT; f = c / TT; Ybf[((size_t)t * NN + d) * 16 + f] = f2bf(acc0);
  c = lane + 64;  t = c % TT; f = c / TT; Ybf[((size_t)t * NN + d) * 16 + f] = f2bf(acc1);
  c = lane + 128; t = c % TT; f = c / TT; Ybf[((size_t)t * NN + d) * 16 + f] = f2bf(acc2);
}

// ---------------- fused weight prep: A = conv_w @ lin_top, bfv = conv_b @ lin_top + lin_b
__global__ void k_prep(const float* __restrict__ czw, const float* __restrict__ czb,
                       const float* __restrict__ lzw, const float* __restrict__ lzb,
                       const float* __restrict__ crw, const float* __restrict__ crb,
                       const float* __restrict__ lrw, const float* __restrict__ lrb,
                       const float* __restrict__ chw, const float* __restrict__ chb,
                       const float* __restrict__ lhw, const float* __restrict__ lhb,
                       float* __restrict__ A, float* __restrict__ bfv) {
  const float *cw, *cb, *lw, *lb;
  if (blockIdx.x == 0)      { cw = czw; cb = czb; lw = lzw; lb = lzb; }
  else if (blockIdx.x == 1) { cw = crw; cb = crb; lw = lrw; lb = lrb; }
  else                      { cw = chw; cb = chb; lw = lhw; lb = lhb; }
  float* Ao = A + blockIdx.x * 2048;
  float* bo = bfv + blockIdx.x * 128;
  for (int idx = threadIdx.x; idx < 2048; idx += 256) {
    int f = idx >> 7, j = idx & 127;
    float acc = 0.f;
    for (int k = 0; k < 128; k++) acc = fmaf(cw[f * 128 + k], lw[k * 128 + j], acc);
    Ao[idx] = acc;
  }
  for (int j = threadIdx.x; j < 128; j += 256) {
    float acc = lb[j];
    for (int k = 0; k < 128; k++) acc = fmaf(cb[k], lw[k * 128 + j], acc);
    bo[j] = acc;
  }
}

// ---------------- main fused GRU + attention + output (MFMA, bf16 hi/lo) ----
// 8 waves, 64 rows/block. D^T = W^T h^T; wave w owns weight cols 16w..16w+15
// as persistent A-frags. Attention fused into phase A. R8: inline fragment
// reads (1 live frag instead of 8 preloaded) + per-nt sc write to cut ~35
// regs of live range -> fit the 256-unified-reg budget (R7 spilled 299 MB).
__global__ __launch_bounds__(512, 1) __attribute__((amdgpu_waves_per_eu(2)))
void k_main(
    const unsigned short* __restrict__ Ybf, const float* __restrict__ A,
    const float* __restrict__ bfv,
    const float* __restrict__ lzw, const float* __restrict__ lrw, const float* __restrict__ lhw,
    const float* __restrict__ a1w, const float* __restrict__ a1b,
    const float* __restrict__ a2w, const float* __restrict__ a2b,
    const float* __restrict__ ow, const float* __restrict__ ob,
    float* __restrict__ out) {
  const int HS = 136, YS = 40;
  __shared__ __align__(16) unsigned char smem[43008];
  unsigned short* h_hi = (unsigned short*)smem;                  // 64*136*2 = 17408
  unsigned short* h_lo = (unsigned short*)(smem + 17408);        // 17408
  unsigned short* y_bf = (unsigned short*)(smem + 34816);        // 64*40*2 = 5120
  float* sc = (float*)(smem + 39936);                            // 64*9*4 = 2304
  // epilogue aliases (used after the final barrier):
  float* ctxb = (float*)smem;                                    // 64*136*4 = 34816
  float* owb  = (float*)(smem + 34816);                          // 8192

  const int tid = threadIdx.x;
  const int w = tid >> 6;
  const int lane = tid & 63;
  const int ln = lane & 15;
  const int lg = lane >> 4;
  const int kg = 8 * lg;
  const int cw = 16 * w + ln;      // weight column (A-operand row)
  const int co = 16 * w + 4 * lg;  // own C-cell column base
  const int base = blockIdx.x * 64;

  for (int i = tid; i < 64 * 136; i += 512) { h_hi[i] = 0; h_lo[i] = 0; }
  // zero y_bf K-tail (cols 16..39): read by MFMA fragments but never staged.
  // Disjoint from y_0 staging (cols 0..15) -> no WW race.
  for (int i = tid; i < 64 * 40; i += 512) {
    if ((i % YS) >= 16) y_bf[i] = 0;
  }

  // persistent weight fragments (split bf16)
  v8s whZ[4], wlZ[4], whR[4], wlR[4], whH[4], wlH[4], waA[4];
  v8s afZ, afR, afH;
#pragma unroll
  for (int ks = 0; ks < 4; ks++) {
#pragma unroll
    for (int j = 0; j < 8; j++) {
      int krow = 128 + 32 * ks + kg + j;  // h-part rows of lin weights
      float vz = lzw[krow * HH + cw];
      float vr = lrw[krow * HH + cw];
      float vh = lhw[krow * HH + cw];
      float va = a1w[(32 * ks + kg + j) * HH + cw];
      unsigned short hb;
      hb = f2bf(vz); whZ[ks][j] = (short)hb; wlZ[ks][j] = (short)f2bf(vz - bf2f(hb));
      hb = f2bf(vr); whR[ks][j] = (short)hb; wlR[ks][j] = (short)f2bf(vr - bf2f(hb));
      hb = f2bf(vh); whH[ks][j] = (short)hb; wlH[ks][j] = (short)f2bf(vh - bf2f(hb));
      waA[ks][j] = (short)f2bf(va);
    }
  }
#pragma unroll
  for (int j = 0; j < 8; j++) {
    int f = (kg + j) & 15;
    afZ[j] = (lg < 2) ? (short)f2bf(A[f * HH + cw]) : (short)0;
    afR[j] = (lg < 2) ? (short)f2bf(A[2048 + f * HH + cw]) : (short)0;
    afH[j] = (lg < 2) ? (short)f2bf(A[4096 + f * HH + cw]) : (short)0;
  }

  const float4 bz4 = *(const float4*)&bfv[co];
  const float4 br4 = *(const float4*)&bfv[128 + co];
  const float4 bh4 = *(const float4*)&bfv[256 + co];
  const float4 ab4 = *(const float4*)&a1b[co];
  const float4 a2v = *(const float4*)&a2w[co];
  const float b2 = a2b[0];

  v4f ctx[4], az[4], ar[4], ho[4];
  float mrun[4], srun[4];
#pragma unroll
  for (int nt = 0; nt < 4; nt++) {
    ctx[nt] = (v4f){0.f, 0.f, 0.f, 0.f};
    mrun[nt] = -1e30f; srun[nt] = 0.f;
  }
  {  // stage y_0 (cols 0..15 only; tail zeroed above)
    int rw = tid >> 3, fp = (tid & 7) * 2;
    int gr = base + rw;
    unsigned int v = 0;
    if (gr < NN) v = *(const unsigned int*)&Ybf[(size_t)gr * 16 + fp];
    *(unsigned int*)&y_bf[rw * YS + fp] = v;
  }
  __syncthreads();

  for (int t = 0; t < TT; t++) {
    // ---- phase A: z, r gates + attention score of current h (= h_{t-1}) ----
#pragma unroll
    for (int nt = 0; nt < 4; nt++) {
      const int hb = (16 * nt + ln) * HS;
      v8s yf = *(const v8s*)&y_bf[(16 * nt + ln) * YS + kg];
      v4f za = (v4f){bz4.x, bz4.y, bz4.z, bz4.w};
      v4f ra = (v4f){br4.x, br4.y, br4.z, br4.w};
      v4f ga = (v4f){ab4.x, ab4.y, ab4.z, ab4.w};
      v4f zb = (v4f){0.f, 0.f, 0.f, 0.f};
      v4f rb = zb, gb = zb;
      za = MFMA(afZ, yf, za);
      ra = MFMA(afR, yf, ra);
#pragma unroll
      for (int ks = 0; ks < 4; ks++) {  // six independent accumulator chains
        v8s hf = *(const v8s*)&h_hi[hb + 32 * ks + kg];
        za = MFMA(whZ[ks], hf, za);
        ra = MFMA(whR[ks], hf, ra);
        ga = MFMA(waA[ks], hf, ga);
        zb = MFMA(wlZ[ks], hf, zb);
        rb = MFMA(wlR[ks], hf, rb);
      }
#pragma unroll
      for (int ks = 0; ks < 4; ks++) {
        v8s lf = *(const v8s*)&h_lo[hb + 32 * ks + kg];
        zb = MFMA(whZ[ks], lf, zb);
        rb = MFMA(whR[ks], lf, rb);
        gb = MFMA(waA[ks], lf, gb);
      }
      az[nt] = za + zb;
      ar[nt] = ra + rb;
      v4f g = ga + gb;
      float pp = fmaxf(g[0], 0.f) * a2v.x + fmaxf(g[1], 0.f) * a2v.y +
                 fmaxf(g[2], 0.f) * a2v.z + fmaxf(g[3], 0.f) * a2v.w;
      pp += __shfl_xor(pp, 16, 64);
      pp += __shfl_xor(pp, 32, 64);
      if (lane < 16) sc[(16 * nt + lane) * 9 + w] = pp;
    }
    __syncthreads();  // h reads done; sc visible

    // ---- phase B: softmax update (scores of h_{t-1}), then u = h*r ----
#pragma unroll
    for (int nt = 0; nt < 4; nt++) {
      const int idx = (16 * nt + ln) * HS + co;
      uint2 hh2 = *(const uint2*)&h_hi[idx];
      uint2 ll2 = *(const uint2*)&h_lo[idx];
      ho[nt][0] = __uint_as_float(hh2.x << 16) + __uint_as_float(ll2.x << 16);
      ho[nt][1] = __uint_as_float(hh2.x & 0xFFFF0000u) + __uint_as_float(ll2.x & 0xFFFF0000u);
      ho[nt][2] = __uint_as_float(hh2.y << 16) + __uint_as_float(ll2.y << 16);
      ho[nt][3] = __uint_as_float(hh2.y & 0xFFFF0000u) + __uint_as_float(ll2.y & 0xFFFF0000u);
    }
    if (t > 0) {  // h_0 = 0 is not an hs element; skip its score
#pragma unroll
      for (int nt = 0; nt < 4; nt++) {
        const float* sr = &sc[(16 * nt + ln) * 9];
        float e = b2 + sr[0] + sr[1] + sr[2] + sr[3] + sr[4] + sr[5] + sr[6] + sr[7];
        float mn = fmaxf(mrun[nt], e);
        float al = __expf(mrun[nt] - mn);
        float be = __expf(e - mn);
        srun[nt] = srun[nt] * al + be;
        mrun[nt] = mn;
#pragma unroll
        for (int r = 0; r < 4; r++) ctx[nt][r] = ctx[nt][r] * al + be * ho[nt][r];
      }
    }
#pragma unroll
    for (int nt = 0; nt < 4; nt++) {
      const int idx = (16 * nt + ln) * HS + co;
      float u0 = ho[nt][0] / (1.f + __expf(-ar[nt][0]));
      float u1 = ho[nt][1] / (1.f + __expf(-ar[nt][1]));
      float u2 = ho[nt][2] / (1.f + __expf(-ar[nt][2]));
      float u3 = ho[nt][3] / (1.f + __expf(-ar[nt][3]));
      unsigned int uh01 = cvt_pk_bf16(u0, u1);
      unsigned int uh23 = cvt_pk_bf16(u2, u3);
      *(uint2*)&h_hi[idx] = make_uint2(uh01, uh23);
      float l0 = u0 - __uint_as_float(uh01 << 16);
      float l1 = u1 - __uint_as_float(uh01 & 0xFFFF0000u);
      float l2 = u2 - __uint_as_float(uh23 << 16);
      float l3 = u3 - __uint_as_float(uh23 & 0xFFFF0000u);
      *(uint2*)&h_lo[idx] = make_uint2(cvt_pk_bf16(l0, l1), cvt_pk_bf16(l2, l3));
    }
    __syncthreads();  // u visible

    // ---- phase C: candidate gate ----
    v4f hn[4];
#pragma unroll
    for (int nt = 0; nt < 4; nt++) {
      const int hb = (16 * nt + ln) * HS;
      v8s yf = *(const v8s*)&y_bf[(16 * nt + ln) * YS + kg];
      v4f ha = (v4f){bh4.x, bh4.y, bh4.z, bh4.w};
      v4f hbv = (v4f){0.f, 0.f, 0.f, 0.f};
      ha = MFMA(afH, yf, ha);
#pragma unroll
      for (int ks = 0; ks < 4; ks++) {
        v8s uf = *(const v8s*)&h_hi[hb + 32 * ks + kg];
        ha = MFMA(whH[ks], uf, ha);
        hbv = MFMA(wlH[ks], uf, hbv);
      }
#pragma unroll
      for (int ks = 0; ks < 4; ks++) {
        v8s ul = *(const v8s*)&h_lo[hb + 32 * ks + kg];
        hbv = MFMA(whH[ks], ul, hbv);
      }
      v4f acch = ha + hbv;
#pragma unroll
      for (int r = 0; r < 4; r++) {
        float zz = 1.f / (1.f + __expf(-az[nt][r]));
        float th = 2.f / (1.f + __expf(-2.f * acch[r])) - 1.f;
        hn[nt][r] = zz * ho[nt][r] + (1.f - zz) * th;
      }
    }
    __syncthreads();  // all u reads done

    // ---- write h_new + stage y_{t+1} ----
#pragma unroll
    for (int nt = 0; nt < 4; nt++) {
      const int idx = (16 * nt + ln) * HS + co;
      unsigned int nh01 = cvt_pk_bf16(hn[nt][0], hn[nt][1]);
      unsigned int nh23 = cvt_pk_bf16(hn[nt][2], hn[nt][3]);
      *(uint2*)&h_hi[idx] = make_uint2(nh01, nh23);
      float l0 = hn[nt][0] - __uint_as_float(nh01 << 16);
      float l1 = hn[nt][1] - __uint_as_float(nh01 & 0xFFFF0000u);
      float l2 = hn[nt][2] - __uint_as_float(nh23 << 16);
      float l3 = hn[nt][3] - __uint_as_float(nh23 & 0xFFFF0000u);
      *(uint2*)&h_lo[idx] = make_uint2(cvt_pk_bf16(l0, l1), cvt_pk_bf16(l2, l3));
    }
    if (t < TT - 1) {
      int rw = tid >> 3, fp = (tid & 7) * 2;
      int gr = base + rw;
      unsigned int v = 0;
      if (gr < NN) v = *(const unsigned int*)&Ybf[((size_t)(t + 1) * NN + gr) * 16 + fp];
      *(unsigned int*)&y_bf[rw * YS + fp] = v;
    }
    __syncthreads();  // h_new + y_{t+1} visible
  }

  // ---- final attention pass for h_12 ----
  {
#pragma unroll
    for (int nt = 0; nt < 4; nt++) {
      const int hb = (16 * nt + ln) * HS;
      v4f ga = (v4f){ab4.x, ab4.y, ab4.z, ab4.w};
      v4f gb = (v4f){0.f, 0.f, 0.f, 0.f};
#pragma unroll
      for (int ks = 0; ks < 4; ks++) {
        v8s hf = *(const v8s*)&h_hi[hb + 32 * ks + kg];
        ga = MFMA(waA[ks], hf, ga);
      }
#pragma unroll
      for (int ks = 0; ks < 4; ks++) {
        v8s lf = *(const v8s*)&h_lo[hb + 32 * ks + kg];
        gb = MFMA(waA[ks], lf, gb);
      }
      v4f g = ga + gb;
      float pp = fmaxf(g[0], 0.f) * a2v.x + fmaxf(g[1], 0.f) * a2v.y +
                 fmaxf(g[2], 0.f) * a2v.z + fmaxf(g[3], 0.f) * a2v.w;
      pp += __shfl_xor(pp, 16, 64);
      pp += __shfl_xor(pp, 32, 64);
      if (lane < 16) sc[(16 * nt + lane) * 9 + w] = pp;
    }
    __syncthreads();
#pragma unroll
    for (int nt = 0; nt < 4; nt++) {
      const int idx = (16 * nt + ln) * HS + co;
      uint2 hh2 = *(const uint2*)&h_hi[idx];
      uint2 ll2 = *(const uint2*)&h_lo[idx];
      float hv0 = __uint_as_float(hh2.x << 16) + __uint_as_float(ll2.x << 16);
      float hv1 = __uint_as_float(hh2.x & 0xFFFF0000u) + __uint_as_float(ll2.x & 0xFFFF0000u);
      float hv2 = __uint_as_float(hh2.y << 16) + __uint_as_float(ll2.y << 16);
      float hv3 = __uint_as_float(hh2.y & 0xFFFF0000u) + __uint_as_float(ll2.y & 0xFFFF0000u);
      const float* sr = &sc[(16 * nt + ln) * 9];
      float e = b2 + sr[0] + sr[1] + sr[2] + sr[3] + sr[4] + sr[5] + sr[6] + sr[7];
      float mn = fmaxf(mrun[nt], e);
      float al = __expf(mrun[nt] - mn);
      float be = __expf(e - mn);
      srun[nt] = srun[nt] * al + be;
      ctx[nt][0] = ctx[nt][0] * al + be * hv0;
      ctx[nt][1] = ctx[nt][1] * al + be * hv1;
      ctx[nt][2] = ctx[nt][2] * al + be * hv2;
      ctx[nt][3] = ctx[nt][3] * al + be * hv3;
    }
  }
  __syncthreads();  // safe to alias h/y/sc arena

  // ---- epilogue: out = (ctx/s) @ out_w + out_b ----
#pragma unroll
  for (int nt = 0; nt < 4; nt++) {
    float inv = 1.f / srun[nt];
    *(float4*)&ctxb[(16 * nt + ln) * 136 + co] =
        make_float4(ctx[nt][0] * inv, ctx[nt][1] * inv, ctx[nt][2] * inv, ctx[nt][3] * inv);
  }
  for (int i = tid; i < 2048; i += 512) owb[i] = ow[i];
  __syncthreads();
#pragma unroll
  for (int pp = 0; pp < 2; pp++) {
    int idx = tid + pp * 512;
    int n = idx >> 4, o = idx & 15;
    float acc = ob[o];
    const float* cr = &ctxb[n * 136];
#pragma unroll 8
    for (int c = 0; c < 128; c++) acc = fmaf(cr[c], owb[c * 16 + o], acc);
    int gn = base + n;
    if (gn < NN) out[gn * 16 + o] = acc;
  }
}

extern "C" void kernel_launch(void* const* d_in, const int* in_sizes, int n_in,
                              void* d_out, int out_size, void* d_ws, size_t ws_size,
                              hipStream_t stream) {
  const float* x   = (const float*)d_in[0];
  const int*   ei  = (const int*)d_in[1];
  const float* ew  = (const float*)d_in[2];
  const float* czw = (const float*)d_in[3],  *czb = (const float*)d_in[4];
  const float* crw = (const float*)d_in[5],  *crb = (const float*)d_in[6];
  const float* chw = (const float*)d_in[7],  *chb = (const float*)d_in[8];
  const float* lzw = (const float*)d_in[9],  *lzb = (const float*)d_in[10];
  const float* lrw = (const float*)d_in[11], *lrb = (const float*)d_in[12];
  const float* lhw = (const float*)d_in[13], *lhb = (const float*)d_in[14];
  const float* a1w = (const float*)d_in[15], *a1b = (const float*)d_in[16];
  const float* a2w = (const float*)d_in[17], *a2b = (const float*)d_in[18];
  const float* ow  = (const float*)d_in[19], *ob  = (const float*)d_in[20];

  float* ws = (float*)d_ws;
  float* deg   = ws;                       // N f32 (becomes dinv)
  int*   cnt   = (int*)(ws + 50048);       // N int (histogram, then cursor)
  int*   row   = (int*)(ws + 100096);      // N+1 int
  int*   csr_s = (int*)(ws + 150400);      // E int
  float* csr_w = ws + 950400;              // E f32
  float* A     = ws + 1750400;             // 3*16*128
  float* bfv   = ws + 1756544;             // 3*128
  unsigned short* Ybf = (unsigned short*)(ws + 1756928);  // [T][N][16] bf16
  float* out = (float*)d_out;

  hipMemsetAsync(ws, 0, 100096 * sizeof(float), stream);  // deg + cnt
  k_degcnt<<<3125, 256, 0, stream>>>(ei, ew, deg, cnt);
  k_dinv<<<196, 256, 0, stream>>>(deg);
  k_scan<<<1, 1024, 0, stream>>>(cnt, row);
  hipMemsetAsync(cnt, 0, 50000 * sizeof(int), stream);
  k_scatter<<<3125, 256, 0, stream>>>(ei, ew, deg, row, cnt, csr_s, csr_w);
  k_gather<<<12500, 256, 0, stream>>>(row, csr_s, csr_w, deg, x, Ybf);
  k_prep<<<3, 256, 0, stream>>>(czw, czb, lzw, lzb, crw, crb, lrw, lrb,
                                chw, chb, lhw, lhb, A, bfv);
  k_main<<<782, 512, 0, stream>>>(Ybf, A, bfv, lzw, lrw, lhw,
                                  a1w, a1b, a2w, a2b, ow, ob, out);
}

// Round 9
// 731.359 us; speedup vs baseline: 1.3153x; 1.3153x over previous
//
#include <hip/hip_runtime.h>
#include <cstddef>

#define NN 50000
#define TT 12
#define HH 128
#define EE 800000

typedef short v8s __attribute__((ext_vector_type(8)));
typedef float v4f __attribute__((ext_vector_type(4)));
#define MFMA(a, b, c) __builtin_amdgcn_mfma_f32_16x16x32_bf16(a, b, c, 0, 0, 0)

__device__ __forceinline__ unsigned short f2bf(float f) {
  unsigned int u = __float_as_uint(f);
  u += 0x7FFF + ((u >> 16) & 1);
  return (unsigned short)(u >> 16);
}
__device__ __forceinline__ float bf2f(unsigned short b) {
  return __uint_as_float(((unsigned int)b) << 16);
}
// HW packed f32->bf16 (low16 = a, high16 = b). Rounding mode irrelevant for
// hi/lo splits: lo captures the residual exactly.
__device__ __forceinline__ unsigned int cvt_pk_bf16(float a, float b) {
  unsigned int r;
  asm("v_cvt_pk_bf16_f32 %0, %1, %2" : "=v"(r) : "v"(a), "v"(b));
  return r;
}

// ---------------- degree + CSR count (one pass over edges) ----------------
__global__ void k_degcnt(const int* __restrict__ ei, const float* __restrict__ ew,
                         float* __restrict__ deg, int* __restrict__ cnt) {
  int e = blockIdx.x * 256 + threadIdx.x;
  if (e < EE) {
    int d = ei[EE + e];
    atomicAdd(&deg[d], ew[e]);
    atomicAdd(&cnt[d], 1);
  }
}

__global__ void k_dinv(float* __restrict__ deg) {
  int n = blockIdx.x * 256 + threadIdx.x;
  if (n < NN) deg[n] = rsqrtf(deg[n] + 1.0f);  // self-loop weight 1 included
}

__global__ void k_scan(const int* __restrict__ cnt, int* __restrict__ row) {
  __shared__ int ps[1024];
  int tid = threadIdx.x;
  const int CH = 49;  // 1024*49 >= NN
  int b0 = tid * CH;
  int s = 0;
  for (int i = 0; i < CH; i++) { int idx = b0 + i; if (idx < NN) s += cnt[idx]; }
  ps[tid] = s;
  __syncthreads();
  for (int off = 1; off < 1024; off <<= 1) {
    int v = (tid >= off) ? ps[tid - off] : 0;
    __syncthreads();
    ps[tid] += v;
    __syncthreads();
  }
  int bb = (tid > 0) ? ps[tid - 1] : 0;
  for (int i = 0; i < CH; i++) {
    int idx = b0 + i;
    if (idx < NN) { row[idx] = bb; bb += cnt[idx]; }
  }
  if (tid == 1023) row[NN] = bb;
}

__global__ void k_scatter(const int* __restrict__ ei, const float* __restrict__ ew,
                          const float* __restrict__ dinv, const int* __restrict__ row,
                          int* __restrict__ cur, int2* __restrict__ csr) {
  int e = blockIdx.x * 256 + threadIdx.x;
  if (e >= EE) return;
  int s = ei[e], d = ei[EE + e];
  int pos = row[d] + atomicAdd(&cur[d], 1);
  float nrm = dinv[s] * ew[e] * dinv[d];
  csr[pos] = make_int2(s, __float_as_int(nrm));
}

// one wave per dst node; lane covers 3 of the 192 (f,t) columns.
// CSR packed int2 + 2-deep prefetch to shorten the dependent-load chain.
__global__ void k_gather(const int* __restrict__ row, const int2* __restrict__ csr,
                         const float* __restrict__ dinv,
                         const float* __restrict__ x, unsigned short* __restrict__ Ybf) {
  int d = blockIdx.x * 4 + (threadIdx.x >> 6);
  if (d >= NN) return;
  int lane = threadIdx.x & 63;
  float acc0, acc1, acc2;
  {
    float dv = dinv[d]; dv *= dv;  // self loop
    const float* xr = x + (size_t)d * 192;
    acc0 = dv * xr[lane]; acc1 = dv * xr[lane + 64]; acc2 = dv * xr[lane + 128];
  }
  int kb = row[d], ke = row[d + 1];
  if (kb < ke) {
    int2 nxt = csr[kb];
    for (int k = kb; k < ke; k++) {
      int2 cur = nxt;
      if (k + 1 < ke) nxt = csr[k + 1];
      const float* xr = x + (size_t)cur.x * 192;
      float wv = __int_as_float(cur.y);
      acc0 = fmaf(wv, xr[lane], acc0);
      acc1 = fmaf(wv, xr[lane + 64], acc1);
      acc2 = fmaf(wv, xr[lane + 128], acc2);
    }
  }
  int c, t, f;
  c = lane;       t = c % TT; f = c / TT; Ybf[((size_t)t * NN + d) * 16 + f] = f2bf(acc0);
  c = lane + 64;  t = c % TT; f = c / TT; Ybf[((size_t)t * NN + d) * 16 + f] = f2bf(acc1);
  c = lane + 128; t = c % TT; f = c / TT; Ybf[((size_t)t * NN + d) * 16 + f] = f2bf(acc2);
}

// ---------------- fused weight prep: A = conv_w @ lin_top, bfv = conv_b @ lin_top + lin_b
__global__ void k_prep(const float* __restrict__ czw, const float* __restrict__ czb,
                       const float* __restrict__ lzw, const float* __restrict__ lzb,
                       const float* __restrict__ crw, const float* __restrict__ crb,
                       const float* __restrict__ lrw, const float* __restrict__ lrb,
                       const float* __restrict__ chw, const float* __restrict__ chb,
                       const float* __restrict__ lhw, const float* __restrict__ lhb,
                       float* __restrict__ A, float* __restrict__ bfv) {
  const float *cw, *cb, *lw, *lb;
  if (blockIdx.x == 0)      { cw = czw; cb = czb; lw = lzw; lb = lzb; }
  else if (blockIdx.x == 1) { cw = crw; cb = crb; lw = lrw; lb = lrb; }
  else                      { cw = chw; cb = chb; lw = lhw; lb = lhb; }
  float* Ao = A + blockIdx.x * 2048;
  float* bo = bfv + blockIdx.x * 128;
  for (int idx = threadIdx.x; idx < 2048; idx += 256) {
    int f = idx >> 7, j = idx & 127;
    float acc = 0.f;
    for (int k = 0; k < 128; k++) acc = fmaf(cw[f * 128 + k], lw[k * 128 + j], acc);
    Ao[idx] = acc;
  }
  for (int j = threadIdx.x; j < 128; j += 256) {
    float acc = lb[j];
    for (int k = 0; k < 128; k++) acc = fmaf(cb[k], lw[k * 128 + j], acc);
    bo[j] = acc;
  }
}

// ---------------- main fused GRU + attention + output (MFMA) ----------------
// 8 waves, 64 rows/block. D^T = W^T h^T; wave w owns weight cols 16w..16w+15
// as persistent A-frags. Attention fused into phase A. R9: weights are pure
// bf16 (W_lo fragments DROPPED: -48 VGPR, -12 MFMA/nt/t) -> peak reg demand
// ~212 < 256 budget, no spills (R7/R8 spilled 300-364 MB). h keeps the hi/lo
// dynamic split in LDS (register-free precision). Evidence for the precision
// cut: absmax was exactly 2^-10 in ALL rounds incl. pure-fp32 R1 -> floor is
// harness-side; W bf16-rounding adds ~2e-4 preact error, est. <2e-3 at out.
__global__ __launch_bounds__(512, 1) __attribute__((amdgpu_waves_per_eu(2)))
void k_main(
    const unsigned short* __restrict__ Ybf, const float* __restrict__ A,
    const float* __restrict__ bfv,
    const float* __restrict__ lzw, const float* __restrict__ lrw, const float* __restrict__ lhw,
    const float* __restrict__ a1w, const float* __restrict__ a1b,
    const float* __restrict__ a2w, const float* __restrict__ a2b,
    const float* __restrict__ ow, const float* __restrict__ ob,
    float* __restrict__ out) {
  const int HS = 136, YS = 40;
  __shared__ __align__(16) unsigned char smem[43008];
  unsigned short* h_hi = (unsigned short*)smem;                  // 64*136*2 = 17408
  unsigned short* h_lo = (unsigned short*)(smem + 17408);        // 17408
  unsigned short* y_bf = (unsigned short*)(smem + 34816);        // 64*40*2 = 5120
  float* sc = (float*)(smem + 39936);                            // 64*9*4 = 2304
  // epilogue aliases (used after the final barrier):
  float* ctxb = (float*)smem;                                    // 64*136*4 = 34816
  float* owb  = (float*)(smem + 34816);                          // 8192

  const int tid = threadIdx.x;
  const int w = tid >> 6;
  const int lane = tid & 63;
  const int ln = lane & 15;
  const int lg = lane >> 4;
  const int kg = 8 * lg;
  const int cw = 16 * w + ln;      // weight column (A-operand row)
  const int co = 16 * w + 4 * lg;  // own C-cell column base
  const int base = blockIdx.x * 64;

  for (int i = tid; i < 64 * 136; i += 512) { h_hi[i] = 0; h_lo[i] = 0; }
  // zero y_bf K-tail (cols 16..39): read by MFMA fragments but never staged.
  // Disjoint from y_0 staging (cols 0..15) -> no WW race.
  for (int i = tid; i < 64 * 40; i += 512) {
    if ((i % YS) >= 16) y_bf[i] = 0;
  }

  // persistent weight fragments (pure bf16; h-side hi/lo carries precision)
  v8s whZ[4], whR[4], whH[4], waA[4];
  v8s afZ, afR, afH;
#pragma unroll
  for (int ks = 0; ks < 4; ks++) {
#pragma unroll
    for (int j = 0; j < 8; j++) {
      int krow = 128 + 32 * ks + kg + j;  // h-part rows of lin weights
      whZ[ks][j] = (short)f2bf(lzw[krow * HH + cw]);
      whR[ks][j] = (short)f2bf(lrw[krow * HH + cw]);
      whH[ks][j] = (short)f2bf(lhw[krow * HH + cw]);
      waA[ks][j] = (short)f2bf(a1w[(32 * ks + kg + j) * HH + cw]);
    }
  }
#pragma unroll
  for (int j = 0; j < 8; j++) {
    int f = (kg + j) & 15;
    afZ[j] = (lg < 2) ? (short)f2bf(A[f * HH + cw]) : (short)0;
    afR[j] = (lg < 2) ? (short)f2bf(A[2048 + f * HH + cw]) : (short)0;
    afH[j] = (lg < 2) ? (short)f2bf(A[4096 + f * HH + cw]) : (short)0;
  }

  const float4 bz4 = *(const float4*)&bfv[co];
  const float4 br4 = *(const float4*)&bfv[128 + co];
  const float4 bh4 = *(const float4*)&bfv[256 + co];
  const float4 ab4 = *(const float4*)&a1b[co];
  const float4 a2v = *(const float4*)&a2w[co];
  const float b2 = a2b[0];

  v4f ctx[4], az[4], ar[4], ho[4];
  float mrun[4], srun[4];
#pragma unroll
  for (int nt = 0; nt < 4; nt++) {
    ctx[nt] = (v4f){0.f, 0.f, 0.f, 0.f};
    mrun[nt] = -1e30f; srun[nt] = 0.f;
  }
  {  // stage y_0 (cols 0..15 only; tail zeroed above)
    int rw = tid >> 3, fp = (tid & 7) * 2;
    int gr = base + rw;
    unsigned int v = 0;
    if (gr < NN) v = *(const unsigned int*)&Ybf[(size_t)gr * 16 + fp];
    *(unsigned int*)&y_bf[rw * YS + fp] = v;
  }
  __syncthreads();

  for (int t = 0; t < TT; t++) {
    // ---- phase A: z, r gates + attention score of current h (= h_{t-1}) ----
#pragma unroll
    for (int nt = 0; nt < 4; nt++) {
      const int hb = (16 * nt + ln) * HS;
      v8s yf = *(const v8s*)&y_bf[(16 * nt + ln) * YS + kg];
      v4f za = (v4f){bz4.x, bz4.y, bz4.z, bz4.w};
      v4f ra = (v4f){br4.x, br4.y, br4.z, br4.w};
      v4f ga = (v4f){ab4.x, ab4.y, ab4.z, ab4.w};
      v4f zb = (v4f){0.f, 0.f, 0.f, 0.f};
      v4f rb = zb, gb = zb;
      za = MFMA(afZ, yf, za);
      ra = MFMA(afR, yf, ra);
#pragma unroll
      for (int ks = 0; ks < 4; ks++) {  // six independent accumulator chains
        v8s hf = *(const v8s*)&h_hi[hb + 32 * ks + kg];
        za = MFMA(whZ[ks], hf, za);
        ra = MFMA(whR[ks], hf, ra);
        ga = MFMA(waA[ks], hf, ga);
      }
#pragma unroll
      for (int ks = 0; ks < 4; ks++) {
        v8s lf = *(const v8s*)&h_lo[hb + 32 * ks + kg];
        zb = MFMA(whZ[ks], lf, zb);
        rb = MFMA(whR[ks], lf, rb);
        gb = MFMA(waA[ks], lf, gb);
      }
      az[nt] = za + zb;
      ar[nt] = ra + rb;
      v4f g = ga + gb;
      float pp = fmaxf(g[0], 0.f) * a2v.x + fmaxf(g[1], 0.f) * a2v.y +
                 fmaxf(g[2], 0.f) * a2v.z + fmaxf(g[3], 0.f) * a2v.w;
      pp += __shfl_xor(pp, 16, 64);
      pp += __shfl_xor(pp, 32, 64);
      if (lane < 16) sc[(16 * nt + lane) * 9 + w] = pp;
    }
    __syncthreads();  // h reads done; sc visible

    // ---- phase B: softmax update (scores of h_{t-1}), then u = h*r ----
#pragma unroll
    for (int nt = 0; nt < 4; nt++) {
      const int idx = (16 * nt + ln) * HS + co;
      uint2 hh2 = *(const uint2*)&h_hi[idx];
      uint2 ll2 = *(const uint2*)&h_lo[idx];
      ho[nt][0] = __uint_as_float(hh2.x << 16) + __uint_as_float(ll2.x << 16);
      ho[nt][1] = __uint_as_float(hh2.x & 0xFFFF0000u) + __uint_as_float(ll2.x & 0xFFFF0000u);
      ho[nt][2] = __uint_as_float(hh2.y << 16) + __uint_as_float(ll2.y << 16);
      ho[nt][3] = __uint_as_float(hh2.y & 0xFFFF0000u) + __uint_as_float(ll2.y & 0xFFFF0000u);
    }
    if (t > 0) {  // h_0 = 0 is not an hs element; skip its score
#pragma unroll
      for (int nt = 0; nt < 4; nt++) {
        const float* sr = &sc[(16 * nt + ln) * 9];
        float e = b2 + sr[0] + sr[1] + sr[2] + sr[3] + sr[4] + sr[5] + sr[6] + sr[7];
        float mn = fmaxf(mrun[nt], e);
        float al = __expf(mrun[nt] - mn);
        float be = __expf(e - mn);
        srun[nt] = srun[nt] * al + be;
        mrun[nt] = mn;
#pragma unroll
        for (int r = 0; r < 4; r++) ctx[nt][r] = ctx[nt][r] * al + be * ho[nt][r];
      }
    }
#pragma unroll
    for (int nt = 0; nt < 4; nt++) {
      const int idx = (16 * nt + ln) * HS + co;
      float u0 = ho[nt][0] / (1.f + __expf(-ar[nt][0]));
      float u1 = ho[nt][1] / (1.f + __expf(-ar[nt][1]));
      float u2 = ho[nt][2] / (1.f + __expf(-ar[nt][2]));
      float u3 = ho[nt][3] / (1.f + __expf(-ar[nt][3]));
      unsigned int uh01 = cvt_pk_bf16(u0, u1);
      unsigned int uh23 = cvt_pk_bf16(u2, u3);
      *(uint2*)&h_hi[idx] = make_uint2(uh01, uh23);
      float l0 = u0 - __uint_as_float(uh01 << 16);
      float l1 = u1 - __uint_as_float(uh01 & 0xFFFF0000u);
      float l2 = u2 - __uint_as_float(uh23 << 16);
      float l3 = u3 - __uint_as_float(uh23 & 0xFFFF0000u);
      *(uint2*)&h_lo[idx] = make_uint2(cvt_pk_bf16(l0, l1), cvt_pk_bf16(l2, l3));
    }
    __syncthreads();  // u visible

    // ---- phase C: candidate gate ----
    v4f hn[4];
#pragma unroll
    for (int nt = 0; nt < 4; nt++) {
      const int hb = (16 * nt + ln) * HS;
      v8s yf = *(const v8s*)&y_bf[(16 * nt + ln) * YS + kg];
      v4f ha = (v4f){bh4.x, bh4.y, bh4.z, bh4.w};
      v4f hbv = (v4f){0.f, 0.f, 0.f, 0.f};
      ha = MFMA(afH, yf, ha);
#pragma unroll
      for (int ks = 0; ks < 4; ks++) {
        v8s uf = *(const v8s*)&h_hi[hb + 32 * ks + kg];
        ha = MFMA(whH[ks], uf, ha);
      }
#pragma unroll
      for (int ks = 0; ks < 4; ks++) {
        v8s ul = *(const v8s*)&h_lo[hb + 32 * ks + kg];
        hbv = MFMA(whH[ks], ul, hbv);
      }
      v4f acch = ha + hbv;
#pragma unroll
      for (int r = 0; r < 4; r++) {
        float zz = 1.f / (1.f + __expf(-az[nt][r]));
        float th = 2.f / (1.f + __expf(-2.f * acch[r])) - 1.f;
        hn[nt][r] = zz * ho[nt][r] + (1.f - zz) * th;
      }
    }
    __syncthreads();  // all u reads done

    // ---- write h_new + stage y_{t+1} ----
#pragma unroll
    for (int nt = 0; nt < 4; nt++) {
      const int idx = (16 * nt + ln) * HS + co;
      unsigned int nh01 = cvt_pk_bf16(hn[nt][0], hn[nt][1]);
      unsigned int nh23 = cvt_pk_bf16(hn[nt][2], hn[nt][3]);
      *(uint2*)&h_hi[idx] = make_uint2(nh01, nh23);
      float l0 = hn[nt][0] - __uint_as_float(nh01 << 16);
      float l1 = hn[nt][1] - __uint_as_float(nh01 & 0xFFFF0000u);
      float l2 = hn[nt][2] - __uint_as_float(nh23 << 16);
      float l3 = hn[nt][3] - __uint_as_float(nh23 & 0xFFFF0000u);
      *(uint2*)&h_lo[idx] = make_uint2(cvt_pk_bf16(l0, l1), cvt_pk_bf16(l2, l3));
    }
    if (t < TT - 1) {
      int rw = tid >> 3, fp = (tid & 7) * 2;
      int gr = base + rw;
      unsigned int v = 0;
      if (gr < NN) v = *(const unsigned int*)&Ybf[((size_t)(t + 1) * NN + gr) * 16 + fp];
      *(unsigned int*)&y_bf[rw * YS + fp] = v;
    }
    __syncthreads();  // h_new + y_{t+1} visible
  }

  // ---- final attention pass for h_12 ----
  {
#pragma unroll
    for (int nt = 0; nt < 4; nt++) {
      const int hb = (16 * nt + ln) * HS;
      v4f ga = (v4f){ab4.x, ab4.y, ab4.z, ab4.w};
      v4f gb = (v4f){0.f, 0.f, 0.f, 0.f};
#pragma unroll
      for (int ks = 0; ks < 4; ks++) {
        v8s hf = *(const v8s*)&h_hi[hb + 32 * ks + kg];
        ga = MFMA(waA[ks], hf, ga);
      }
#pragma unroll
      for (int ks = 0; ks < 4; ks++) {
        v8s lf = *(const v8s*)&h_lo[hb + 32 * ks + kg];
        gb = MFMA(waA[ks], lf, gb);
      }
      v4f g = ga + gb;
      float pp = fmaxf(g[0], 0.f) * a2v.x + fmaxf(g[1], 0.f) * a2v.y +
                 fmaxf(g[2], 0.f) * a2v.z + fmaxf(g[3], 0.f) * a2v.w;
      pp += __shfl_xor(pp, 16, 64);
      pp += __shfl_xor(pp, 32, 64);
      if (lane < 16) sc[(16 * nt + lane) * 9 + w] = pp;
    }
    __syncthreads();
#pragma unroll
    for (int nt = 0; nt < 4; nt++) {
      const int idx = (16 * nt + ln) * HS + co;
      uint2 hh2 = *(const uint2*)&h_hi[idx];
      uint2 ll2 = *(const uint2*)&h_lo[idx];
      float hv0 = __uint_as_float(hh2.x << 16) + __uint_as_float(ll2.x << 16);
      float hv1 = __uint_as_float(hh2.x & 0xFFFF0000u) + __uint_as_float(ll2.x & 0xFFFF0000u);
      float hv2 = __uint_as_float(hh2.y << 16) + __uint_as_float(ll2.y << 16);
      float hv3 = __uint_as_float(hh2.y & 0xFFFF0000u) + __uint_as_float(ll2.y & 0xFFFF0000u);
      const float* sr = &sc[(16 * nt + ln) * 9];
      float e = b2 + sr[0] + sr[1] + sr[2] + sr[3] + sr[4] + sr[5] + sr[6] + sr[7];
      float mn = fmaxf(mrun[nt], e);
      float al = __expf(mrun[nt] - mn);
      float be = __expf(e - mn);
      srun[nt] = srun[nt] * al + be;
      ctx[nt][0] = ctx[nt][0] * al + be * hv0;
      ctx[nt][1] = ctx[nt][1] * al + be * hv1;
      ctx[nt][2] = ctx[nt][2] * al + be * hv2;
      ctx[nt][3] = ctx[nt][3] * al + be * hv3;
    }
  }
  __syncthreads();  // safe to alias h/y/sc arena

  // ---- epilogue: out = (ctx/s) @ out_w + out_b ----
#pragma unroll
  for (int nt = 0; nt < 4; nt++) {
    float inv = 1.f / srun[nt];
    *(float4*)&ctxb[(16 * nt + ln) * 136 + co] =
        make_float4(ctx[nt][0] * inv, ctx[nt][1] * inv, ctx[nt][2] * inv, ctx[nt][3] * inv);
  }
  for (int i = tid; i < 2048; i += 512) owb[i] = ow[i];
  __syncthreads();
#pragma unroll
  for (int pp = 0; pp < 2; pp++) {
    int idx = tid + pp * 512;
    int n = idx >> 4, o = idx & 15;
    float acc = ob[o];
    const float* cr = &ctxb[n * 136];
#pragma unroll 8
    for (int c = 0; c < 128; c++) acc = fmaf(cr[c], owb[c * 16 + o], acc);
    int gn = base + n;
    if (gn < NN) out[gn * 16 + o] = acc;
  }
}

extern "C" void kernel_launch(void* const* d_in, const int* in_sizes, int n_in,
                              void* d_out, int out_size, void* d_ws, size_t ws_size,
                              hipStream_t stream) {
  const float* x   = (const float*)d_in[0];
  const int*   ei  = (const int*)d_in[1];
  const float* ew  = (const float*)d_in[2];
  const float* czw = (const float*)d_in[3],  *czb = (const float*)d_in[4];
  const float* crw = (const float*)d_in[5],  *crb = (const float*)d_in[6];
  const float* chw = (const float*)d_in[7],  *chb = (const float*)d_in[8];
  const float* lzw = (const float*)d_in[9],  *lzb = (const float*)d_in[10];
  const float* lrw = (const float*)d_in[11], *lrb = (const float*)d_in[12];
  const float* lhw = (const float*)d_in[13], *lhb = (const float*)d_in[14];
  const float* a1w = (const float*)d_in[15], *a1b = (const float*)d_in[16];
  const float* a2w = (const float*)d_in[17], *a2b = (const float*)d_in[18];
  const float* ow  = (const float*)d_in[19], *ob  = (const float*)d_in[20];

  float* ws = (float*)d_ws;
  float* deg   = ws;                       // N f32 (becomes dinv)
  int*   cnt   = (int*)(ws + 50048);       // N int (histogram, then cursor)
  int*   row   = (int*)(ws + 100096);      // N+1 int
  int2*  csr   = (int2*)(ws + 150400);     // E x int2 (src, w-bits)
  float* A     = ws + 1750400;             // 3*16*128
  float* bfv   = ws + 1756544;             // 3*128
  unsigned short* Ybf = (unsigned short*)(ws + 1756928);  // [T][N][16] bf16
  float* out = (float*)d_out;

  hipMemsetAsync(ws, 0, 100096 * sizeof(float), stream);  // deg + cnt
  k_degcnt<<<3125, 256, 0, stream>>>(ei, ew, deg, cnt);
  k_dinv<<<196, 256, 0, stream>>>(deg);
  k_scan<<<1, 1024, 0, stream>>>(cnt, row);
  hipMemsetAsync(cnt, 0, 50000 * sizeof(int), stream);
  k_scatter<<<3125, 256, 0, stream>>>(ei, ew, deg, row, cnt, csr);
  k_gather<<<12500, 256, 0, stream>>>(row, csr, deg, x, Ybf);
  k_prep<<<3, 256, 0, stream>>>(czw, czb, lzw, lzb, crw, crb, lrw, lrb,
                                chw, chb, lhw, lhb, A, bfv);
  k_main<<<782, 512, 0, stream>>>(Ybf, A, bfv, lzw, lrw, lhw,
                                  a1w, a1b, a2w, a2b, ow, ob, out);
}

// Round 10
// 671.179 us; speedup vs baseline: 1.4333x; 1.0897x over previous
//
#include <hip/hip_runtime.h>
#include <cstddef>

#define NN 50000
#define TT 12
#define HH 128
#define EE 800000

typedef short v8s __attribute__((ext_vector_type(8)));
typedef float v4f __attribute__((ext_vector_type(4)));
#define MFMA(a, b, c) __builtin_amdgcn_mfma_f32_16x16x32_bf16(a, b, c, 0, 0, 0)

__device__ __forceinline__ unsigned short f2bf(float f) {
  unsigned int u = __float_as_uint(f);
  u += 0x7FFF + ((u >> 16) & 1);
  return (unsigned short)(u >> 16);
}
__device__ __forceinline__ float bf2f(unsigned short b) {
  return __uint_as_float(((unsigned int)b) << 16);
}
// HW packed f32->bf16 (low16 = a, high16 = b).
__device__ __forceinline__ unsigned int cvt_pk_bf16(float a, float b) {
  unsigned int r;
  asm("v_cvt_pk_bf16_f32 %0, %1, %2" : "=v"(r) : "v"(a), "v"(b));
  return r;
}
// v_rcp_f32: ~1ulp reciprocal, 1 instruction. Avoids the ~11-inst IEEE fdiv
// expansion (v_div_scale/v_div_fmas/v_div_fixup) the compiler emits for x/y.
__device__ __forceinline__ float frcp(float x) {
  return __builtin_amdgcn_rcpf(x);
}

// ---------------- degree + CSR count (one pass over edges) ----------------
__global__ void k_degcnt(const int* __restrict__ ei, const float* __restrict__ ew,
                         float* __restrict__ deg, int* __restrict__ cnt) {
  int e = blockIdx.x * 256 + threadIdx.x;
  if (e < EE) {
    int d = ei[EE + e];
    atomicAdd(&deg[d], ew[e]);
    atomicAdd(&cnt[d], 1);
  }
}

__global__ void k_dinv(float* __restrict__ deg) {
  int n = blockIdx.x * 256 + threadIdx.x;
  if (n < NN) deg[n] = rsqrtf(deg[n] + 1.0f);  // self-loop weight 1 included
}

__global__ void k_scan(const int* __restrict__ cnt, int* __restrict__ row) {
  __shared__ int ps[1024];
  int tid = threadIdx.x;
  const int CH = 49;  // 1024*49 >= NN
  int b0 = tid * CH;
  int s = 0;
  for (int i = 0; i < CH; i++) { int idx = b0 + i; if (idx < NN) s += cnt[idx]; }
  ps[tid] = s;
  __syncthreads();
  for (int off = 1; off < 1024; off <<= 1) {
    int v = (tid >= off) ? ps[tid - off] : 0;
    __syncthreads();
    ps[tid] += v;
    __syncthreads();
  }
  int bb = (tid > 0) ? ps[tid - 1] : 0;
  for (int i = 0; i < CH; i++) {
    int idx = b0 + i;
    if (idx < NN) { row[idx] = bb; bb += cnt[idx]; }
  }
  if (tid == 1023) row[NN] = bb;
}

__global__ void k_scatter(const int* __restrict__ ei, const float* __restrict__ ew,
                          const float* __restrict__ dinv, const int* __restrict__ row,
                          int* __restrict__ cur, int2* __restrict__ csr) {
  int e = blockIdx.x * 256 + threadIdx.x;
  if (e >= EE) return;
  int s = ei[e], d = ei[EE + e];
  int pos = row[d] + atomicAdd(&cur[d], 1);
  float nrm = dinv[s] * ew[e] * dinv[d];
  csr[pos] = make_int2(s, __float_as_int(nrm));
}

// one wave per dst node; lane covers 3 of the 192 (f,t) columns.
// CSR packed int2 + 2-deep prefetch to shorten the dependent-load chain.
__global__ void k_gather(const int* __restrict__ row, const int2* __restrict__ csr,
                         const float* __restrict__ dinv,
                         const float* __restrict__ x, unsigned short* __restrict__ Ybf) {
  int d = blockIdx.x * 4 + (threadIdx.x >> 6);
  if (d >= NN) return;
  int lane = threadIdx.x & 63;
  float acc0, acc1, acc2;
  {
    float dv = dinv[d]; dv *= dv;  // self loop
    const float* xr = x + (size_t)d * 192;
    acc0 = dv * xr[lane]; acc1 = dv * xr[lane + 64]; acc2 = dv * xr[lane + 128];
  }
  int kb = row[d], ke = row[d + 1];
  if (kb < ke) {
    int2 nxt = csr[kb];
    for (int k = kb; k < ke; k++) {
      int2 cur = nxt;
      if (k + 1 < ke) nxt = csr[k + 1];
      const float* xr = x + (size_t)cur.x * 192;
      float wv = __int_as_float(cur.y);
      acc0 = fmaf(wv, xr[lane], acc0);
      acc1 = fmaf(wv, xr[lane + 64], acc1);
      acc2 = fmaf(wv, xr[lane + 128], acc2);
    }
  }
  int c, t, f;
  c = lane;       t = c % TT; f = c / TT; Ybf[((size_t)t * NN + d) * 16 + f] = f2bf(acc0);
  c = lane + 64;  t = c % TT; f = c / TT; Ybf[((size_t)t * NN + d) * 16 + f] = f2bf(acc1);
  c = lane + 128; t = c % TT; f = c / TT; Ybf[((size_t)t * NN + d) * 16 + f] = f2bf(acc2);
}

// ---------------- fused weight prep: A = conv_w @ lin_top, bfv = conv_b @ lin_top + lin_b
__global__ void k_prep(const float* __restrict__ czw, const float* __restrict__ czb,
                       const float* __restrict__ lzw, const float* __restrict__ lzb,
                       const float* __restrict__ crw, const float* __restrict__ crb,
                       const float* __restrict__ lrw, const float* __restrict__ lrb,
                       const float* __restrict__ chw, const float* __restrict__ chb,
                       const float* __restrict__ lhw, const float* __restrict__ lhb,
                       float* __restrict__ A, float* __restrict__ bfv) {
  const float *cw, *cb, *lw, *lb;
  if (blockIdx.x == 0)      { cw = czw; cb = czb; lw = lzw; lb = lzb; }
  else if (blockIdx.x == 1) { cw = crw; cb = crb; lw = lrw; lb = lrb; }
  else                      { cw = chw; cb = chb; lw = lhw; lb = lhb; }
  float* Ao = A + blockIdx.x * 2048;
  float* bo = bfv + blockIdx.x * 128;
  for (int idx = threadIdx.x; idx < 2048; idx += 256) {
    int f = idx >> 7, j = idx & 127;
    float acc = 0.f;
    for (int k = 0; k < 128; k++) acc = fmaf(cw[f * 128 + k], lw[k * 128 + j], acc);
    Ao[idx] = acc;
  }
  for (int j = threadIdx.x; j < 128; j += 256) {
    float acc = lb[j];
    for (int k = 0; k < 128; k++) acc = fmaf(cb[k], lw[k * 128 + j], acc);
    bo[j] = acc;
  }
}

// ---------------- main fused GRU + attention + output (MFMA) ----------------
// 8 waves, 64 rows/block. D^T = W^T h^T; wave w owns weight cols 16w..16w+15
// as persistent bf16 A-frags (R9). h lives in LDS as dynamic hi/lo bf16 split.
// R10: (1) v_rcp_f32 for all sigmoid/tanh denominators (kills ~530 VALU
// inst/thread/t of IEEE fdiv expansion), (2) own h cells carried in regs
// across t (phase-B LDS re-read + unpack deleted), (3) async y_{t+1} stage:
// global load issued at loop top, ds_write at loop end (T14).
__global__ __launch_bounds__(512, 1) __attribute__((amdgpu_waves_per_eu(2)))
void k_main(
    const unsigned short* __restrict__ Ybf, const float* __restrict__ A,
    const float* __restrict__ bfv,
    const float* __restrict__ lzw, const float* __restrict__ lrw, const float* __restrict__ lhw,
    const float* __restrict__ a1w, const float* __restrict__ a1b,
    const float* __restrict__ a2w, const float* __restrict__ a2b,
    const float* __restrict__ ow, const float* __restrict__ ob,
    float* __restrict__ out) {
  const int HS = 136, YS = 40;
  __shared__ __align__(16) unsigned char smem[43008];
  unsigned short* h_hi = (unsigned short*)smem;                  // 64*136*2 = 17408
  unsigned short* h_lo = (unsigned short*)(smem + 17408);        // 17408
  unsigned short* y_bf = (unsigned short*)(smem + 34816);        // 64*40*2 = 5120
  float* sc = (float*)(smem + 39936);                            // 64*9*4 = 2304
  // epilogue aliases (used after the final barrier):
  float* ctxb = (float*)smem;                                    // 64*136*4 = 34816
  float* owb  = (float*)(smem + 34816);                          // 8192

  const int tid = threadIdx.x;
  const int w = tid >> 6;
  const int lane = tid & 63;
  const int ln = lane & 15;
  const int lg = lane >> 4;
  const int kg = 8 * lg;
  const int cw = 16 * w + ln;      // weight column (A-operand row)
  const int co = 16 * w + 4 * lg;  // own C-cell column base
  const int base = blockIdx.x * 64;

  for (int i = tid; i < 64 * 136; i += 512) { h_hi[i] = 0; h_lo[i] = 0; }
  // zero y_bf K-tail (cols 16..39): read by MFMA fragments but never staged.
  for (int i = tid; i < 64 * 40; i += 512) {
    if ((i % YS) >= 16) y_bf[i] = 0;
  }

  // persistent weight fragments (pure bf16; h-side hi/lo carries precision)
  v8s whZ[4], whR[4], whH[4], waA[4];
  v8s afZ, afR, afH;
#pragma unroll
  for (int ks = 0; ks < 4; ks++) {
#pragma unroll
    for (int j = 0; j < 8; j++) {
      int krow = 128 + 32 * ks + kg + j;  // h-part rows of lin weights
      whZ[ks][j] = (short)f2bf(lzw[krow * HH + cw]);
      whR[ks][j] = (short)f2bf(lrw[krow * HH + cw]);
      whH[ks][j] = (short)f2bf(lhw[krow * HH + cw]);
      waA[ks][j] = (short)f2bf(a1w[(32 * ks + kg + j) * HH + cw]);
    }
  }
#pragma unroll
  for (int j = 0; j < 8; j++) {
    int f = (kg + j) & 15;
    afZ[j] = (lg < 2) ? (short)f2bf(A[f * HH + cw]) : (short)0;
    afR[j] = (lg < 2) ? (short)f2bf(A[2048 + f * HH + cw]) : (short)0;
    afH[j] = (lg < 2) ? (short)f2bf(A[4096 + f * HH + cw]) : (short)0;
  }

  const float4 bz4 = *(const float4*)&bfv[co];
  const float4 br4 = *(const float4*)&bfv[128 + co];
  const float4 bh4 = *(const float4*)&bfv[256 + co];
  const float4 ab4 = *(const float4*)&a1b[co];
  const float4 a2v = *(const float4*)&a2w[co];
  const float b2 = a2b[0];

  v4f ctx[4], az[4], ar[4], hn[4];  // hn = own h cells, carried in regs
  float mrun[4], srun[4];
#pragma unroll
  for (int nt = 0; nt < 4; nt++) {
    ctx[nt] = (v4f){0.f, 0.f, 0.f, 0.f};
    hn[nt] = (v4f){0.f, 0.f, 0.f, 0.f};
    mrun[nt] = -1e30f; srun[nt] = 0.f;
  }
  const int yrw = tid >> 3, yfp = (tid & 7) * 2;
  const int ygr = base + yrw;
  {  // stage y_0 (cols 0..15 only; tail zeroed above)
    unsigned int v = 0;
    if (ygr < NN) v = *(const unsigned int*)&Ybf[(size_t)ygr * 16 + yfp];
    *(unsigned int*)&y_bf[yrw * YS + yfp] = v;
  }
  __syncthreads();

  for (int t = 0; t < TT; t++) {
    // issue next-t staging load EARLY (latency hides under phases A-C)
    unsigned int ynext = 0;
    if (t < TT - 1 && ygr < NN)
      ynext = *(const unsigned int*)&Ybf[((size_t)(t + 1) * NN + ygr) * 16 + yfp];

    // ---- phase A: z, r gates + attention score of h_{t-1} ----
#pragma unroll
    for (int nt = 0; nt < 4; nt++) {
      const int hb = (16 * nt + ln) * HS;
      v8s yf = *(const v8s*)&y_bf[(16 * nt + ln) * YS + kg];
      v4f za = (v4f){bz4.x, bz4.y, bz4.z, bz4.w};
      v4f ra = (v4f){br4.x, br4.y, br4.z, br4.w};
      v4f ga = (v4f){ab4.x, ab4.y, ab4.z, ab4.w};
      v4f zb = (v4f){0.f, 0.f, 0.f, 0.f};
      v4f rb = zb, gb = zb;
      za = MFMA(afZ, yf, za);
      ra = MFMA(afR, yf, ra);
#pragma unroll
      for (int ks = 0; ks < 4; ks++) {  // six independent accumulator chains
        v8s hf = *(const v8s*)&h_hi[hb + 32 * ks + kg];
        za = MFMA(whZ[ks], hf, za);
        ra = MFMA(whR[ks], hf, ra);
        ga = MFMA(waA[ks], hf, ga);
      }
#pragma unroll
      for (int ks = 0; ks < 4; ks++) {
        v8s lf = *(const v8s*)&h_lo[hb + 32 * ks + kg];
        zb = MFMA(whZ[ks], lf, zb);
        rb = MFMA(whR[ks], lf, rb);
        gb = MFMA(waA[ks], lf, gb);
      }
      az[nt] = za + zb;
      ar[nt] = ra + rb;
      v4f g = ga + gb;
      float pp = fmaxf(g[0], 0.f) * a2v.x + fmaxf(g[1], 0.f) * a2v.y +
                 fmaxf(g[2], 0.f) * a2v.z + fmaxf(g[3], 0.f) * a2v.w;
      pp += __shfl_xor(pp, 16, 64);
      pp += __shfl_xor(pp, 32, 64);
      if (lane < 16) sc[(16 * nt + lane) * 9 + w] = pp;
    }
    __syncthreads();  // h reads done; sc visible

    // ---- phase B: online softmax on h_{t-1} (regs), then u = h*r ----
    if (t > 0) {  // h_0 = 0 is not an hs element; skip its score
#pragma unroll
      for (int nt = 0; nt < 4; nt++) {
        const float* sr = &sc[(16 * nt + ln) * 9];
        float e = b2 + sr[0] + sr[1] + sr[2] + sr[3] + sr[4] + sr[5] + sr[6] + sr[7];
        float mn = fmaxf(mrun[nt], e);
        float al = __expf(mrun[nt] - mn);
        float be = __expf(e - mn);
        srun[nt] = srun[nt] * al + be;
        mrun[nt] = mn;
#pragma unroll
        for (int r = 0; r < 4; r++) ctx[nt][r] = ctx[nt][r] * al + be * hn[nt][r];
      }
    }
#pragma unroll
    for (int nt = 0; nt < 4; nt++) {
      const int idx = (16 * nt + ln) * HS + co;
      float u0 = hn[nt][0] * frcp(1.f + __expf(-ar[nt][0]));
      float u1 = hn[nt][1] * frcp(1.f + __expf(-ar[nt][1]));
      float u2 = hn[nt][2] * frcp(1.f + __expf(-ar[nt][2]));
      float u3 = hn[nt][3] * frcp(1.f + __expf(-ar[nt][3]));
      unsigned int uh01 = cvt_pk_bf16(u0, u1);
      unsigned int uh23 = cvt_pk_bf16(u2, u3);
      *(uint2*)&h_hi[idx] = make_uint2(uh01, uh23);
      float l0 = u0 - __uint_as_float(uh01 << 16);
      float l1 = u1 - __uint_as_float(uh01 & 0xFFFF0000u);
      float l2 = u2 - __uint_as_float(uh23 << 16);
      float l3 = u3 - __uint_as_float(uh23 & 0xFFFF0000u);
      *(uint2*)&h_lo[idx] = make_uint2(cvt_pk_bf16(l0, l1), cvt_pk_bf16(l2, l3));
    }
    __syncthreads();  // u visible

    // ---- phase C: candidate gate ----
#pragma unroll
    for (int nt = 0; nt < 4; nt++) {
      const int hb = (16 * nt + ln) * HS;
      v8s yf = *(const v8s*)&y_bf[(16 * nt + ln) * YS + kg];
      v4f ha = (v4f){bh4.x, bh4.y, bh4.z, bh4.w};
      v4f hbv = (v4f){0.f, 0.f, 0.f, 0.f};
      ha = MFMA(afH, yf, ha);
#pragma unroll
      for (int ks = 0; ks < 4; ks++) {
        v8s uf = *(const v8s*)&h_hi[hb + 32 * ks + kg];
        ha = MFMA(whH[ks], uf, ha);
      }
#pragma unroll
      for (int ks = 0; ks < 4; ks++) {
        v8s ul = *(const v8s*)&h_lo[hb + 32 * ks + kg];
        hbv = MFMA(whH[ks], ul, hbv);
      }
      v4f acch = ha + hbv;
#pragma unroll
      for (int r = 0; r < 4; r++) {
        float zz = frcp(1.f + __expf(-az[nt][r]));
        float th = 2.f * frcp(1.f + __expf(-2.f * acch[r])) - 1.f;
        hn[nt][r] = zz * hn[nt][r] + (1.f - zz) * th;  // h_t (reg carry)
      }
    }
    __syncthreads();  // all u reads done

    // ---- write h_new + commit prefetched y_{t+1} ----
#pragma unroll
    for (int nt = 0; nt < 4; nt++) {
      const int idx = (16 * nt + ln) * HS + co;
      unsigned int nh01 = cvt_pk_bf16(hn[nt][0], hn[nt][1]);
      unsigned int nh23 = cvt_pk_bf16(hn[nt][2], hn[nt][3]);
      *(uint2*)&h_hi[idx] = make_uint2(nh01, nh23);
      float l0 = hn[nt][0] - __uint_as_float(nh01 << 16);
      float l1 = hn[nt][1] - __uint_as_float(nh01 & 0xFFFF0000u);
      float l2 = hn[nt][2] - __uint_as_float(nh23 << 16);
      float l3 = hn[nt][3] - __uint_as_float(nh23 & 0xFFFF0000u);
      *(uint2*)&h_lo[idx] = make_uint2(cvt_pk_bf16(l0, l1), cvt_pk_bf16(l2, l3));
    }
    if (t < TT - 1) *(unsigned int*)&y_bf[yrw * YS + yfp] = ynext;
    __syncthreads();  // h_new + y_{t+1} visible
  }

  // ---- final attention pass for h_12 (in regs) ----
  {
#pragma unroll
    for (int nt = 0; nt < 4; nt++) {
      const int hb = (16 * nt + ln) * HS;
      v4f ga = (v4f){ab4.x, ab4.y, ab4.z, ab4.w};
      v4f gb = (v4f){0.f, 0.f, 0.f, 0.f};
#pragma unroll
      for (int ks = 0; ks < 4; ks++) {
        v8s hf = *(const v8s*)&h_hi[hb + 32 * ks + kg];
        ga = MFMA(waA[ks], hf, ga);
      }
#pragma unroll
      for (int ks = 0; ks < 4; ks++) {
        v8s lf = *(const v8s*)&h_lo[hb + 32 * ks + kg];
        gb = MFMA(waA[ks], lf, gb);
      }
      v4f g = ga + gb;
      float pp = fmaxf(g[0], 0.f) * a2v.x + fmaxf(g[1], 0.f) * a2v.y +
                 fmaxf(g[2], 0.f) * a2v.z + fmaxf(g[3], 0.f) * a2v.w;
      pp += __shfl_xor(pp, 16, 64);
      pp += __shfl_xor(pp, 32, 64);
      if (lane < 16) sc[(16 * nt + lane) * 9 + w] = pp;
    }
    __syncthreads();
#pragma unroll
    for (int nt = 0; nt < 4; nt++) {
      const float* sr = &sc[(16 * nt + ln) * 9];
      float e = b2 + sr[0] + sr[1] + sr[2] + sr[3] + sr[4] + sr[5] + sr[6] + sr[7];
      float mn = fmaxf(mrun[nt], e);
      float al = __expf(mrun[nt] - mn);
      float be = __expf(e - mn);
      srun[nt] = srun[nt] * al + be;
#pragma unroll
      for (int r = 0; r < 4; r++) ctx[nt][r] = ctx[nt][r] * al + be * hn[nt][r];
    }
  }
  __syncthreads();  // safe to alias h/y/sc arena

  // ---- epilogue: out = (ctx/s) @ out_w + out_b ----
#pragma unroll
  for (int nt = 0; nt < 4; nt++) {
    float inv = frcp(srun[nt]);
    *(float4*)&ctxb[(16 * nt + ln) * 136 + co] =
        make_float4(ctx[nt][0] * inv, ctx[nt][1] * inv, ctx[nt][2] * inv, ctx[nt][3] * inv);
  }
  for (int i = tid; i < 2048; i += 512) owb[i] = ow[i];
  __syncthreads();
#pragma unroll
  for (int pp = 0; pp < 2; pp++) {
    int idx = tid + pp * 512;
    int n = idx >> 4, o = idx & 15;
    float acc = ob[o];
    const float* cr = &ctxb[n * 136];
#pragma unroll 8
    for (int c = 0; c < 128; c++) acc = fmaf(cr[c], owb[c * 16 + o], acc);
    int gn = base + n;
    if (gn < NN) out[gn * 16 + o] = acc;
  }
}

extern "C" void kernel_launch(void* const* d_in, const int* in_sizes, int n_in,
                              void* d_out, int out_size, void* d_ws, size_t ws_size,
                              hipStream_t stream) {
  const float* x   = (const float*)d_in[0];
  const int*   ei  = (const int*)d_in[1];
  const float* ew  = (const float*)d_in[2];
  const float* czw = (const float*)d_in[3],  *czb = (const float*)d_in[4];
  const float* crw = (const float*)d_in[5],  *crb = (const float*)d_in[6];
  const float* chw = (const float*)d_in[7],  *chb = (const float*)d_in[8];
  const float* lzw = (const float*)d_in[9],  *lzb = (const float*)d_in[10];
  const float* lrw = (const float*)d_in[11], *lrb = (const float*)d_in[12];
  const float* lhw = (const float*)d_in[13], *lhb = (const float*)d_in[14];
  const float* a1w = (const float*)d_in[15], *a1b = (const float*)d_in[16];
  const float* a2w = (const float*)d_in[17], *a2b = (const float*)d_in[18];
  const float* ow  = (const float*)d_in[19], *ob  = (const float*)d_in[20];

  float* ws = (float*)d_ws;
  float* deg   = ws;                       // N f32 (becomes dinv)
  int*   cnt   = (int*)(ws + 50048);       // N int (histogram, then cursor)
  int*   row   = (int*)(ws + 100096);      // N+1 int
  int2*  csr   = (int2*)(ws + 150400);     // E x int2 (src, w-bits)
  float* A     = ws + 1750400;             // 3*16*128
  float* bfv   = ws + 1756544;             // 3*128
  unsigned short* Ybf = (unsigned short*)(ws + 1756928);  // [T][N][16] bf16
  float* out = (float*)d_out;

  hipMemsetAsync(ws, 0, 100096 * sizeof(float), stream);  // deg + cnt
  k_degcnt<<<3125, 256, 0, stream>>>(ei, ew, deg, cnt);
  k_dinv<<<196, 256, 0, stream>>>(deg);
  k_scan<<<1, 1024, 0, stream>>>(cnt, row);
  hipMemsetAsync(cnt, 0, 50000 * sizeof(int), stream);
  k_scatter<<<3125, 256, 0, stream>>>(ei, ew, deg, row, cnt, csr);
  k_gather<<<12500, 256, 0, stream>>>(row, csr, deg, x, Ybf);
  k_prep<<<3, 256, 0, stream>>>(czw, czb, lzw, lzb, crw, crb, lrw, lrb,
                                chw, chb, lhw, lhb, A, bfv);
  k_main<<<782, 512, 0, stream>>>(Ybf, A, bfv, lzw, lrw, lhw,
                                  a1w, a1b, a2w, a2b, ow, ob, out);
}